// Round 1
// baseline (343.181 us; speedup 1.0000x reference)
//
#include <hip/hip_runtime.h>

// Shapes
#define BB 16
#define NN 8192
#define DMODEL 256
#define DKK 64
#define DVV 64
#define NQQ 256

#define TOK 64      // tokens per block in score kernel
#define DC 32       // d-chunk
#define ROWP 36     // padded LDS row (32 + 4 floats): 144B, 16B-aligned, bank step 4

// ---------------- prep: qk = q @ w_ks  (256x256), MT = (w_fc @ w_vs)^T (256x256) ----
__global__ __launch_bounds__(256) void prep_kernel(
    const float* __restrict__ q, const float* __restrict__ w_ks,
    const float* __restrict__ w_vs, const float* __restrict__ w_fc,
    float* __restrict__ qk, float* __restrict__ MT) {
  __shared__ float sbuf[DKK];
  const int tid = threadIdx.x;
  const int blk = blockIdx.x;
  if (blk < NQQ) {
    // qk[s][d] = sum_k q[s,k] * w_ks[k,d]
    const int s = blk;
    if (tid < DKK) sbuf[tid] = q[s * DKK + tid];
    __syncthreads();
    float acc = 0.f;
#pragma unroll
    for (int k = 0; k < DKK; ++k) acc = fmaf(sbuf[k], w_ks[k * DMODEL + tid], acc);
    qk[s * DMODEL + tid] = acc;
  } else {
    // MT[dm][d] = sum_v w_fc[d,v] * w_vs[v,dm]
    const int dm = blk - NQQ;
    if (tid < DVV) sbuf[tid] = w_vs[tid * DMODEL + dm];
    __syncthreads();
    float acc = 0.f;
#pragma unroll
    for (int v = 0; v < DVV; ++v) acc = fmaf(w_fc[tid * DVV + v], sbuf[v], acc);
    MT[dm * DMODEL + tid] = acc;
  }
}

// ---------------- main: scores = x @ qk^T, argmax, one-hot write, scatter S ---------
__global__ __launch_bounds__(256) void score_kernel(
    const float* __restrict__ x, const float* __restrict__ qk,
    float* __restrict__ S, float* __restrict__ hard) {
  __shared__ float xs[TOK * ROWP];    // 64 x 32 (padded)  ~9.2 KB
  __shared__ float qks[NQQ * ROWP];   // 256 x 32 (padded) ~36.9 KB
  __shared__ int idx_s[TOK];

  const int tid = threadIdx.x;
  const int b = blockIdx.y;
  const int n0 = blockIdx.x * TOK;
  const int tr = tid >> 5;   // 0..7  -> token group of 8
  const int tc = tid & 31;   // 0..31 -> slot lane

  float acc[8][8];
#pragma unroll
  for (int i = 0; i < 8; ++i)
#pragma unroll
    for (int j = 0; j < 8; ++j) acc[i][j] = 0.f;

  const float* xbase = x + ((size_t)b * NN + n0) * DMODEL;

  for (int dc = 0; dc < DMODEL / DC; ++dc) {
    // stage x tile: 64 rows x 32 cols = 512 float4
#pragma unroll
    for (int it = 0; it < 2; ++it) {
      int u = it * 256 + tid;
      int row = u >> 3, c4 = u & 7;
      float4 v = *(const float4*)(xbase + (size_t)row * DMODEL + dc * DC + c4 * 4);
      *(float4*)(&xs[row * ROWP + c4 * 4]) = v;
    }
    // stage qk tile: 256 rows x 32 cols = 2048 float4
#pragma unroll
    for (int it = 0; it < 8; ++it) {
      int u = it * 256 + tid;
      int row = u >> 3, c4 = u & 7;
      float4 v = *(const float4*)(qk + (size_t)row * DMODEL + dc * DC + c4 * 4);
      *(float4*)(&qks[row * ROWP + c4 * 4]) = v;
    }
    __syncthreads();

#pragma unroll
    for (int d4 = 0; d4 < DC / 4; ++d4) {
      float4 xv[8], qv[8];
#pragma unroll
      for (int i = 0; i < 8; ++i) xv[i] = *(const float4*)(&xs[(tr * 8 + i) * ROWP + d4 * 4]);
#pragma unroll
      for (int j = 0; j < 8; ++j) qv[j] = *(const float4*)(&qks[(j * 32 + tc) * ROWP + d4 * 4]);
#pragma unroll
      for (int i = 0; i < 8; ++i)
#pragma unroll
        for (int j = 0; j < 8; ++j) {
          acc[i][j] = fmaf(xv[i].x, qv[j].x, acc[i][j]);
          acc[i][j] = fmaf(xv[i].y, qv[j].y, acc[i][j]);
          acc[i][j] = fmaf(xv[i].z, qv[j].z, acc[i][j]);
          acc[i][j] = fmaf(xv[i].w, qv[j].w, acc[i][j]);
        }
    }
    __syncthreads();
  }

  // per-token argmax over 256 slots (numpy tie-break: first index wins)
#pragma unroll
  for (int i = 0; i < 8; ++i) {
    float bv = acc[i][0];
    int bs = tc;  // j=0 -> s = tc
#pragma unroll
    for (int j = 1; j < 8; ++j) {
      int s = j * 32 + tc;
      float v = acc[i][j];
      if (v > bv || (v == bv && s < bs)) { bv = v; bs = s; }
    }
#pragma unroll
    for (int off = 16; off >= 1; off >>= 1) {
      float ov = __shfl_xor(bv, off, 64);
      int os = __shfl_xor(bs, off, 64);
      if (ov > bv || (ov == bv && os < bs)) { bv = ov; bs = os; }
    }
    if (tc == 0) idx_s[tr * 8 + i] = bs;
  }
  __syncthreads();

  // hardattn one-hot: 64 rows x 256 = 4096 float4, fully coalesced
  float4* hbase = (float4*)(hard + ((size_t)b * NN + n0) * NQQ);
#pragma unroll
  for (int it = 0; it < 16; ++it) {
    int u = it * 256 + tid;
    int tok = u >> 6;
    int s0 = (u & 63) * 4;
    int tgt = idx_s[tok];
    float4 h;
    h.x = (s0 + 0 == tgt) ? 1.f : 0.f;
    h.y = (s0 + 1 == tgt) ? 1.f : 0.f;
    h.z = (s0 + 2 == tgt) ? 1.f : 0.f;
    h.w = (s0 + 3 == tgt) ? 1.f : 0.f;
    hbase[u] = h;
  }

  // scatter: S[b, idx[t], :] += x[b, n0+t, :]  (coalesced read, one atomic per lane)
  for (int t = 0; t < TOK; ++t) {
    int tgt = idx_s[t];
    float v = xbase[(size_t)t * DMODEL + tid];
    atomicAdd(&S[((size_t)b * NQQ + tgt) * DMODEL + tid], v);
  }
}

// ---------------- out[b,s,d] = sum_dm S[b,s,dm] * MT[dm,d] -------------------------
__global__ __launch_bounds__(256) void out_kernel(
    const float* __restrict__ S, const float* __restrict__ MT,
    float* __restrict__ out) {
  __shared__ float srow[8][DMODEL];
  const int tid = threadIdx.x;
  const int r0 = blockIdx.x * 8;  // rows = b*NQQ + s
#pragma unroll
  for (int i = 0; i < 8; ++i) srow[i][tid] = S[(size_t)(r0 + i) * DMODEL + tid];
  __syncthreads();
  float a[8];
#pragma unroll
  for (int i = 0; i < 8; ++i) a[i] = 0.f;
  for (int dm = 0; dm < DMODEL; ++dm) {
    float m = MT[(size_t)dm * DMODEL + tid];
#pragma unroll
    for (int i = 0; i < 8; ++i) a[i] = fmaf(srow[i][dm], m, a[i]);
  }
#pragma unroll
  for (int i = 0; i < 8; ++i) out[(size_t)(r0 + i) * DMODEL + tid] = a[i];
}

extern "C" void kernel_launch(void* const* d_in, const int* in_sizes, int n_in,
                              void* d_out, int out_size, void* d_ws, size_t ws_size,
                              hipStream_t stream) {
  const float* x   = (const float*)d_in[0];
  const float* q   = (const float*)d_in[1];
  const float* wks = (const float*)d_in[2];
  const float* wvs = (const float*)d_in[3];
  const float* wfc = (const float*)d_in[4];

  float* out  = (float*)d_out;                       // (16,256,256)
  float* hard = out + (size_t)BB * NQQ * DMODEL;     // (16,8192,256)

  float* qk = (float*)d_ws;                          // 256*256
  float* MT = qk + NQQ * DMODEL;                     // 256*256
  float* S  = MT + NQQ * DMODEL;                     // 16*256*256

  hipMemsetAsync(S, 0, (size_t)BB * NQQ * DMODEL * sizeof(float), stream);
  prep_kernel<<<2 * NQQ, 256, 0, stream>>>(q, wks, wvs, wfc, qk, MT);
  score_kernel<<<dim3(NN / TOK, BB), 256, 0, stream>>>(x, qk, S, hard);
  out_kernel<<<(BB * NQQ) / 8, 256, 0, stream>>>(S, MT, out);
}

// Round 2
// 269.225 us; speedup vs baseline: 1.2747x; 1.2747x over previous
//
#include <hip/hip_runtime.h>

#define BB 16
#define NN 8192
#define DMODEL 256
#define DKK 64
#define DVV 64
#define NQQ 256
#define TOK 64
#define MARGIN 0.02f
#define CAP 32768

typedef __attribute__((ext_vector_type(8))) short bf16x8;
typedef __attribute__((ext_vector_type(4))) float f32x4;

// RNE split of f32 into bf16 hi + bf16 lo (x ~= hi + lo, |err| ~ 2^-17 |x|)
__device__ __forceinline__ void split_bf16(float v, unsigned short& h, unsigned short& lo) {
  unsigned u = __float_as_uint(v);
  unsigned hr = (u + 0x7FFFu + ((u >> 16) & 1u)) & 0xFFFF0000u;
  h = (unsigned short)(hr >> 16);
  float r = v - __uint_as_float(hr);
  unsigned ul = __float_as_uint(r);
  lo = (unsigned short)((ul + 0x7FFFu + ((ul >> 16) & 1u)) >> 16);
}

// prep: qk = q @ w_ks (f32, for recheck), split-fragments qhf/qlf, MT = (w_fc @ w_vs)^T
__global__ __launch_bounds__(256) void prep_kernel(
    const float* __restrict__ q, const float* __restrict__ w_ks,
    const float* __restrict__ w_vs, const float* __restrict__ w_fc,
    float* __restrict__ qk, float* __restrict__ MT,
    unsigned short* __restrict__ qhf, unsigned short* __restrict__ qlf) {
  __shared__ float sbuf[DKK];
  const int tid = threadIdx.x;
  const int blk = blockIdx.x;
  if (blk < NQQ) {
    const int s = blk;
    if (tid < DKK) sbuf[tid] = q[s * DKK + tid];
    __syncthreads();
    float acc = 0.f;
#pragma unroll
    for (int k = 0; k < DKK; ++k) acc = fmaf(sbuf[k], w_ks[k * DMODEL + tid], acc);
    qk[s * DMODEL + tid] = acc;
    // fragment layout: elem idx = ((kstep*16 + stile)*64 + (kg*16 + s15))*8 + jj
    int d = tid;
    int kstep = d >> 5, kg = (d >> 3) & 3, jj = d & 7;
    int stile = s >> 4, s15 = s & 15;
    int e = (((kstep * 16 + stile) * 64) + (kg * 16 + s15)) * 8 + jj;
    unsigned short hb, lb;
    split_bf16(acc, hb, lb);
    qhf[e] = hb; qlf[e] = lb;
  } else {
    const int dm = blk - NQQ;
    if (tid < DVV) sbuf[tid] = w_vs[tid * DMODEL + dm];
    __syncthreads();
    float acc = 0.f;
#pragma unroll
    for (int v = 0; v < DVV; ++v) acc = fmaf(w_fc[tid * DVV + v], sbuf[v], acc);
    MT[dm * DMODEL + tid] = acc;
  }
}

// main: split-bf16 MFMA scores, top-2 argmax, ambiguity list, one-hot write, scatter S
__global__ __launch_bounds__(256) void score_kernel(
    const float* __restrict__ x, const unsigned short* __restrict__ qhf,
    const unsigned short* __restrict__ qlf,
    float* __restrict__ S, float* __restrict__ hard,
    unsigned* __restrict__ cnt, unsigned* __restrict__ list) {
  __shared__ unsigned short xs_h[16384];   // [kstep][tile][lane][8] bf16, 32 KB
  __shared__ unsigned short xs_l[16384];   // 32 KB
  __shared__ float rm1[4][TOK];
  __shared__ float rm2[4][TOK];
  __shared__ int   ri1[4][TOK];
  __shared__ int   idx_s[TOK];

  const int tid = threadIdx.x;
  const int w = tid >> 6;       // wave 0..3 -> slot range w*64..w*64+63
  const int l = tid & 63;       // lane
  const int b = blockIdx.y;
  const int n0 = blockIdx.x * TOK;
  const float* xbase = x + ((size_t)b * NN + n0) * DMODEL;
  const float4* xb4 = (const float4*)xbase;

  // ---- stage x tile (64 tok x 256 d) as bf16 hi/lo fragments ----
#pragma unroll
  for (int it = 0; it < 16; ++it) {
    int tok = w * 16 + (it & 1) * 8 + (l >> 3);
    int c4  = (it >> 1) * 8 + (l & 7);           // 8 lanes x 128B contiguous global
    float4 v = xb4[tok * 64 + c4];
    int kstep = c4 >> 3, kg = (c4 >> 1) & 3, j0 = (c4 & 1) * 4;
    int e = (((kstep * 4 + w) * 64) + (kg * 16 + (tok & 15))) * 8 + j0;
    ushort4 hh, ll;
    split_bf16(v.x, hh.x, ll.x);
    split_bf16(v.y, hh.y, ll.y);
    split_bf16(v.z, hh.z, ll.z);
    split_bf16(v.w, hh.w, ll.w);
    *(ushort4*)(&xs_h[e]) = hh;
    *(ushort4*)(&xs_l[e]) = ll;
  }
  __syncthreads();

  // ---- MFMA: 64 tok x 64 slots per wave; acc[tile][stile] ----
  const bf16x8* bh = (const bf16x8*)qhf;
  const bf16x8* bl = (const bf16x8*)qlf;
  f32x4 acc[4][4];
#pragma unroll
  for (int i = 0; i < 4; ++i)
#pragma unroll
    for (int j = 0; j < 4; ++j) acc[i][j] = (f32x4){0.f, 0.f, 0.f, 0.f};

#pragma unroll
  for (int k = 0; k < 8; ++k) {
    bf16x8 Bh[4], Bl[4], Ah[4], Al[4];
#pragma unroll
    for (int j = 0; j < 4; ++j) {
      Bh[j] = bh[(k * 16 + w * 4 + j) * 64 + l];   // L2-resident global, lane-contig
      Bl[j] = bl[(k * 16 + w * 4 + j) * 64 + l];
    }
#pragma unroll
    for (int i = 0; i < 4; ++i) {
      Ah[i] = *(const bf16x8*)(&xs_h[((k * 4 + i) * 64 + l) * 8]);  // conflict-free b128
      Al[i] = *(const bf16x8*)(&xs_l[((k * 4 + i) * 64 + l) * 8]);
    }
#pragma unroll
    for (int i = 0; i < 4; ++i)
#pragma unroll
      for (int j = 0; j < 4; ++j) {
        acc[i][j] = __builtin_amdgcn_mfma_f32_16x16x32_bf16(Ah[i], Bh[j], acc[i][j], 0, 0, 0);
        acc[i][j] = __builtin_amdgcn_mfma_f32_16x16x32_bf16(Ah[i], Bl[j], acc[i][j], 0, 0, 0);
        acc[i][j] = __builtin_amdgcn_mfma_f32_16x16x32_bf16(Al[i], Bh[j], acc[i][j], 0, 0, 0);
      }
  }

  // ---- per-token top-2 over this wave's 64 slots ----
  // C/D layout: col(slot) = l&15, row(token) = (l>>4)*4 + reg
  const int s15 = l & 15, g4 = l >> 4;
#pragma unroll
  for (int i = 0; i < 4; ++i) {
#pragma unroll
    for (int r = 0; r < 4; ++r) {
      float m1 = acc[i][0][r];
      int   i1 = w * 64 + s15;
      float m2 = -1e30f;
#pragma unroll
      for (int j = 1; j < 4; ++j) {
        float v = acc[i][j][r];
        int   s = w * 64 + j * 16 + s15;
        if (v > m1) { m2 = m1; m1 = v; i1 = s; }
        else if (v > m2) m2 = v;
      }
#pragma unroll
      for (int off = 1; off < 16; off <<= 1) {
        float om1 = __shfl_xor(m1, off, 64);
        int   oi1 = __shfl_xor(i1, off, 64);
        float om2 = __shfl_xor(m2, off, 64);
        if (om1 > m1 || (om1 == m1 && oi1 < i1)) { m2 = fmaxf(m1, om2); m1 = om1; i1 = oi1; }
        else { m2 = fmaxf(m2, om1); }
      }
      if (s15 == 0) {
        int t = i * 16 + g4 * 4 + r;
        rm1[w][t] = m1; rm2[w][t] = m2; ri1[w][t] = i1;
      }
    }
  }
  __syncthreads();

  // ---- cross-wave merge (waves cover ascending slot ranges -> first-index natural) ----
  if (tid < TOK) {
    float m1 = rm1[0][tid]; int i1 = ri1[0][tid]; float m2 = rm2[0][tid];
#pragma unroll
    for (int ww = 1; ww < 4; ++ww) {
      float om1 = rm1[ww][tid]; int oi1 = ri1[ww][tid]; float om2 = rm2[ww][tid];
      if (om1 > m1) { m2 = fmaxf(m1, om2); m1 = om1; i1 = oi1; }
      else { m2 = fmaxf(m2, om1); }
    }
    idx_s[tid] = i1;
    if (m1 - m2 <= MARGIN) {   // ambiguous under split-bf16 error -> f32 recheck
      unsigned pos = atomicAdd(cnt, 1u);
      if (pos < CAP) list[pos] = (((unsigned)(b * NN + n0 + tid)) << 8) | (unsigned)i1;
    }
  }
  __syncthreads();

  // ---- one-hot write (provisional; recheck patches flagged tokens) ----
  float4* hbase = (float4*)(hard + ((size_t)b * NN + n0) * NQQ);
#pragma unroll
  for (int it = 0; it < 16; ++it) {
    int u = it * 256 + tid;
    int tok = u >> 6;
    int s0 = (u & 63) * 4;
    int tgt = idx_s[tok];
    float4 h;
    h.x = (s0 + 0 == tgt) ? 1.f : 0.f;
    h.y = (s0 + 1 == tgt) ? 1.f : 0.f;
    h.z = (s0 + 2 == tgt) ? 1.f : 0.f;
    h.w = (s0 + 3 == tgt) ? 1.f : 0.f;
    hbase[u] = h;
  }

  // ---- scatter: S[b, idx[t], :] += x[b, n0+t, :] ----
  for (int t = 0; t < TOK; ++t) {
    int tgt = idx_s[t];
    float v = xbase[(size_t)t * DMODEL + tid];
    atomicAdd(&S[((size_t)b * NQQ + tgt) * DMODEL + tid], v);
  }
}

// recheck: exact-f32 scores for ambiguous tokens; patch one-hot + S on flip
__global__ __launch_bounds__(256) void recheck_kernel(
    const float* __restrict__ x, const float* __restrict__ qk,
    const unsigned* __restrict__ cnt, const unsigned* __restrict__ list,
    float* __restrict__ S, float* __restrict__ hard) {
  __shared__ float xrow[DMODEL];
  __shared__ float sv[NQQ];
  __shared__ int   si[NQQ];
  const int tid = threadIdx.x;
  unsigned nc = cnt[0];
  int nA = (int)(nc < (unsigned)CAP ? nc : (unsigned)CAP);
  for (int e = blockIdx.x; e < nA; e += gridDim.x) {
    unsigned pk = list[e];
    int tokid = (int)(pk >> 8);
    int olds  = (int)(pk & 255u);
    const float* xr = x + (size_t)tokid * DMODEL;
    xrow[tid] = xr[tid];
    __syncthreads();
    const float* qr = qk + (size_t)tid * DMODEL;
    float a = 0.f;
#pragma unroll
    for (int d4 = 0; d4 < 64; ++d4) {   // strict sequential-d order (matches r1 kernel)
      float4 qv = *(const float4*)(qr + d4 * 4);
      float4 xv = *(const float4*)(&xrow[d4 * 4]);
      a = fmaf(xv.x, qv.x, a); a = fmaf(xv.y, qv.y, a);
      a = fmaf(xv.z, qv.z, a); a = fmaf(xv.w, qv.w, a);
    }
    sv[tid] = a; si[tid] = tid;
    __syncthreads();
    for (int s = 128; s >= 1; s >>= 1) {
      if (tid < s) {
        float vo = sv[tid + s]; int io = si[tid + s];
        if (vo > sv[tid] || (vo == sv[tid] && io < si[tid])) { sv[tid] = vo; si[tid] = io; }
      }
      __syncthreads();
    }
    int news = si[0];
    if (news != olds) {
      int bb = tokid >> 13;
      if (tid == 0) {
        hard[(size_t)tokid * NQQ + olds] = 0.f;
        hard[(size_t)tokid * NQQ + news] = 1.f;
      }
      float xv = xrow[tid];
      atomicAdd(&S[((size_t)bb * NQQ + olds) * DMODEL + tid], -xv);
      atomicAdd(&S[((size_t)bb * NQQ + news) * DMODEL + tid],  xv);
    }
    __syncthreads();
  }
}

// out[b,s,d] = sum_dm S[b,s,dm] * MT[dm,d]
__global__ __launch_bounds__(256) void out_kernel(
    const float* __restrict__ S, const float* __restrict__ MT,
    float* __restrict__ out) {
  __shared__ float srow[8][DMODEL];
  const int tid = threadIdx.x;
  const int r0 = blockIdx.x * 8;
#pragma unroll
  for (int i = 0; i < 8; ++i) srow[i][tid] = S[(size_t)(r0 + i) * DMODEL + tid];
  __syncthreads();
  float a[8];
#pragma unroll
  for (int i = 0; i < 8; ++i) a[i] = 0.f;
  for (int dm = 0; dm < DMODEL; ++dm) {
    float m = MT[(size_t)dm * DMODEL + tid];
#pragma unroll
    for (int i = 0; i < 8; ++i) a[i] = fmaf(srow[i][dm], m, a[i]);
  }
#pragma unroll
  for (int i = 0; i < 8; ++i) out[(size_t)(r0 + i) * DMODEL + tid] = a[i];
}

extern "C" void kernel_launch(void* const* d_in, const int* in_sizes, int n_in,
                              void* d_out, int out_size, void* d_ws, size_t ws_size,
                              hipStream_t stream) {
  const float* x   = (const float*)d_in[0];
  const float* q   = (const float*)d_in[1];
  const float* wks = (const float*)d_in[2];
  const float* wvs = (const float*)d_in[3];
  const float* wfc = (const float*)d_in[4];

  float* out  = (float*)d_out;                       // (16,256,256)
  float* hard = out + (size_t)BB * NQQ * DMODEL;     // (16,8192,256)

  float* qk = (float*)d_ws;                          // 65536 f
  float* MT = qk + 65536;                            // 65536 f
  float* S  = MT + 65536;                            // 1048576 f (4 MB)
  unsigned* cnt  = (unsigned*)(S + 1048576);         // 64 u32 (pad)
  unsigned* list = cnt + 64;                         // CAP u32
  unsigned short* qhf = (unsigned short*)(list + CAP);  // 65536 bf16
  unsigned short* qlf = qhf + 65536;                    // 65536 bf16

  hipMemsetAsync(S, 0, (size_t)1048576 * sizeof(float), stream);
  hipMemsetAsync(cnt, 0, 256, stream);
  prep_kernel<<<2 * NQQ, 256, 0, stream>>>(q, wks, wvs, wfc, qk, MT, qhf, qlf);
  score_kernel<<<dim3(NN / TOK, BB), 256, 0, stream>>>(x, qhf, qlf, S, hard, cnt, list);
  recheck_kernel<<<2048, 256, 0, stream>>>(x, qk, cnt, list, S, hard);
  out_kernel<<<(BB * NQQ) / 8, 256, 0, stream>>>(S, MT, out);
}

// Round 3
// 225.788 us; speedup vs baseline: 1.5199x; 1.1924x over previous
//
#include <hip/hip_runtime.h>

#define BB 16
#define NN 8192
#define DMODEL 256
#define DKK 64
#define DVV 64
#define NQQ 256
#define TOK 32
#define MARGIN 0.02f
#define CAP 32768

typedef __attribute__((ext_vector_type(8))) short bf16x8;
typedef __attribute__((ext_vector_type(4))) float f32x4;

// RNE split of f32 into bf16 hi + bf16 lo (x ~= hi + lo, |err| ~ 2^-17 |x|)
__device__ __forceinline__ void split_bf16(float v, unsigned short& h, unsigned short& lo) {
  unsigned u = __float_as_uint(v);
  unsigned hr = (u + 0x7FFFu + ((u >> 16) & 1u)) & 0xFFFF0000u;
  h = (unsigned short)(hr >> 16);
  float r = v - __uint_as_float(hr);
  unsigned ul = __float_as_uint(r);
  lo = (unsigned short)((ul + 0x7FFFu + ((ul >> 16) & 1u)) >> 16);
}

// prep: qk = q @ w_ks (f32, for recheck), split-fragments qhf/qlf, MT = (w_fc @ w_vs)^T
__global__ __launch_bounds__(256) void prep_kernel(
    const float* __restrict__ q, const float* __restrict__ w_ks,
    const float* __restrict__ w_vs, const float* __restrict__ w_fc,
    float* __restrict__ qk, float* __restrict__ MT,
    unsigned short* __restrict__ qhf, unsigned short* __restrict__ qlf) {
  __shared__ float sbuf[DKK];
  const int tid = threadIdx.x;
  const int blk = blockIdx.x;
  if (blk < NQQ) {
    const int s = blk;
    if (tid < DKK) sbuf[tid] = q[s * DKK + tid];
    __syncthreads();
    float acc = 0.f;
#pragma unroll
    for (int k = 0; k < DKK; ++k) acc = fmaf(sbuf[k], w_ks[k * DMODEL + tid], acc);
    qk[s * DMODEL + tid] = acc;
    // B fragment layout: elem idx = ((kstep*16 + stile)*64 + (kg*16 + s15))*8 + jj
    int d = tid;
    int kstep = d >> 5, kg = (d >> 3) & 3, jj = d & 7;
    int stile = s >> 4, s15 = s & 15;
    int e = (((kstep * 16 + stile) * 64) + (kg * 16 + s15)) * 8 + jj;
    unsigned short hb, lb;
    split_bf16(acc, hb, lb);
    qhf[e] = hb; qlf[e] = lb;
  } else {
    const int dm = blk - NQQ;
    if (tid < DVV) sbuf[tid] = w_vs[tid * DMODEL + dm];
    __syncthreads();
    float acc = 0.f;
#pragma unroll
    for (int v = 0; v < DVV; ++v) acc = fmaf(w_fc[tid * DVV + v], sbuf[v], acc);
    MT[dm * DMODEL + tid] = acc;
  }
}

// main: split-bf16 MFMA scores, top-2 argmax, ambiguity list, one-hot write, scatter S
__global__ __launch_bounds__(256, 4) void score_kernel(
    const float* __restrict__ x, const unsigned short* __restrict__ qhf,
    const unsigned short* __restrict__ qlf,
    float* __restrict__ S, float* __restrict__ hard,
    unsigned* __restrict__ cnt, unsigned* __restrict__ list) {
  __shared__ unsigned short xs_h[8192];   // [kstep(8)][tile(2)][lane(64)][8] bf16, 16 KB
  __shared__ unsigned short xs_l[8192];   // 16 KB
  __shared__ float rm1[4][TOK];
  __shared__ float rm2[4][TOK];
  __shared__ int   ri1[4][TOK];
  __shared__ int   idx_s[TOK];

  const int tid = threadIdx.x;
  const int w = tid >> 6;       // wave 0..3 -> slot range w*64..w*64+63
  const int l = tid & 63;       // lane
  const int b = blockIdx.y;
  const int n0 = blockIdx.x * TOK;
  const float* xbase = x + ((size_t)b * NN + n0) * DMODEL;
  const float4* xb4 = (const float4*)xbase;

  // ---- stage x tile (32 tok x 256 d) as bf16 hi/lo fragments ----
  {
    const int tok = w * 8 + (l >> 3);          // 32 tokens
    const int r   = l & 7;
    const int kg  = r >> 1;                    // (c4>>1)&3
    const int j0  = (r & 1) * 4;
    const int i   = tok >> 4;
    const int t15 = tok & 15;
#pragma unroll
    for (int it = 0; it < 8; ++it) {
      int c4 = it * 8 + r;                     // kstep = it
      float4 v = xb4[tok * 64 + c4];
      int e = (((it * 2 + i) * 64) + (kg * 16 + t15)) * 8 + j0;
      ushort4 hh, ll;
      split_bf16(v.x, hh.x, ll.x);
      split_bf16(v.y, hh.y, ll.y);
      split_bf16(v.z, hh.z, ll.z);
      split_bf16(v.w, hh.w, ll.w);
      *(ushort4*)(&xs_h[e]) = hh;
      *(ushort4*)(&xs_l[e]) = ll;
    }
  }
  __syncthreads();

  // ---- MFMA: 32 tok x 64 slots per wave; acc[tile][stile] ----
  const bf16x8* bh = (const bf16x8*)qhf;
  const bf16x8* bl = (const bf16x8*)qlf;
  f32x4 acc[2][4];
#pragma unroll
  for (int i = 0; i < 2; ++i)
#pragma unroll
    for (int j = 0; j < 4; ++j) acc[i][j] = (f32x4){0.f, 0.f, 0.f, 0.f};

#pragma unroll
  for (int k = 0; k < 8; ++k) {
    bf16x8 Bh[4], Bl[4], Ah[2], Al[2];
#pragma unroll
    for (int j = 0; j < 4; ++j) {
      Bh[j] = bh[(k * 16 + w * 4 + j) * 64 + l];   // L2-resident global, lane-contig
      Bl[j] = bl[(k * 16 + w * 4 + j) * 64 + l];
    }
#pragma unroll
    for (int i = 0; i < 2; ++i) {
      Ah[i] = *(const bf16x8*)(&xs_h[((k * 2 + i) * 64 + l) * 8]);  // conflict-free b128
      Al[i] = *(const bf16x8*)(&xs_l[((k * 2 + i) * 64 + l) * 8]);
    }
#pragma unroll
    for (int i = 0; i < 2; ++i)
#pragma unroll
      for (int j = 0; j < 4; ++j) {
        acc[i][j] = __builtin_amdgcn_mfma_f32_16x16x32_bf16(Ah[i], Bh[j], acc[i][j], 0, 0, 0);
        acc[i][j] = __builtin_amdgcn_mfma_f32_16x16x32_bf16(Ah[i], Bl[j], acc[i][j], 0, 0, 0);
        acc[i][j] = __builtin_amdgcn_mfma_f32_16x16x32_bf16(Al[i], Bh[j], acc[i][j], 0, 0, 0);
      }
  }

  // ---- per-token top-2 over this wave's 64 slots ----
  // C/D layout: col(slot) = l&15, row(token) = (l>>4)*4 + reg
  const int s15 = l & 15, g4 = l >> 4;
#pragma unroll
  for (int i = 0; i < 2; ++i) {
#pragma unroll
    for (int r = 0; r < 4; ++r) {
      float m1 = acc[i][0][r];
      int   i1 = w * 64 + s15;
      float m2 = -1e30f;
#pragma unroll
      for (int j = 1; j < 4; ++j) {
        float v = acc[i][j][r];
        int   s = w * 64 + j * 16 + s15;
        if (v > m1) { m2 = m1; m1 = v; i1 = s; }
        else if (v > m2) m2 = v;
      }
#pragma unroll
      for (int off = 1; off < 16; off <<= 1) {
        float om1 = __shfl_xor(m1, off, 64);
        int   oi1 = __shfl_xor(i1, off, 64);
        float om2 = __shfl_xor(m2, off, 64);
        if (om1 > m1 || (om1 == m1 && oi1 < i1)) { m2 = fmaxf(m1, om2); m1 = om1; i1 = oi1; }
        else { m2 = fmaxf(m2, om1); }
      }
      if (s15 == 0) {
        int t = i * 16 + g4 * 4 + r;
        rm1[w][t] = m1; rm2[w][t] = m2; ri1[w][t] = i1;
      }
    }
  }
  __syncthreads();

  // ---- cross-wave merge (waves cover ascending slot ranges -> first-index natural) ----
  if (tid < TOK) {
    float m1 = rm1[0][tid]; int i1 = ri1[0][tid]; float m2 = rm2[0][tid];
#pragma unroll
    for (int ww = 1; ww < 4; ++ww) {
      float om1 = rm1[ww][tid]; int oi1 = ri1[ww][tid]; float om2 = rm2[ww][tid];
      if (om1 > m1) { m2 = fmaxf(m1, om2); m1 = om1; i1 = oi1; }
      else { m2 = fmaxf(m2, om1); }
    }
    idx_s[tid] = i1;
    if (m1 - m2 <= MARGIN) {   // ambiguous under split-bf16 error -> f32 recheck
      unsigned pos = atomicAdd(cnt, 1u);
      if (pos < CAP) list[pos] = (((unsigned)(b * NN + n0 + tid)) << 8) | (unsigned)i1;
    }
  }
  __syncthreads();

  // ---- one-hot write (provisional; recheck patches flagged tokens) ----
  float4* hbase = (float4*)(hard + ((size_t)b * NN + n0) * NQQ);
#pragma unroll
  for (int it = 0; it < 8; ++it) {
    int u = it * 256 + tid;
    int tok = u >> 6;
    int s0 = (u & 63) * 4;
    int tgt = idx_s[tok];
    float4 h;
    h.x = (s0 + 0 == tgt) ? 1.f : 0.f;
    h.y = (s0 + 1 == tgt) ? 1.f : 0.f;
    h.z = (s0 + 2 == tgt) ? 1.f : 0.f;
    h.w = (s0 + 3 == tgt) ? 1.f : 0.f;
    hbase[u] = h;
  }

  // ---- scatter: S[b, idx[t], :] += x[b, n0+t, :] ----
  for (int t = 0; t < TOK; ++t) {
    int tgt = idx_s[t];
    float v = xbase[(size_t)t * DMODEL + tid];
    atomicAdd(&S[((size_t)b * NQQ + tgt) * DMODEL + tid], v);
  }
}

// recheck: exact-f32 scores for ambiguous tokens; patch one-hot + S on flip
__global__ __launch_bounds__(256) void recheck_kernel(
    const float* __restrict__ x, const float* __restrict__ qk,
    const unsigned* __restrict__ cnt, const unsigned* __restrict__ list,
    float* __restrict__ S, float* __restrict__ hard) {
  __shared__ float xrow[DMODEL];
  __shared__ float sv[NQQ];
  __shared__ int   si[NQQ];
  const int tid = threadIdx.x;
  unsigned nc = cnt[0];
  int nA = (int)(nc < (unsigned)CAP ? nc : (unsigned)CAP);
  for (int e = blockIdx.x; e < nA; e += gridDim.x) {
    unsigned pk = list[e];
    int tokid = (int)(pk >> 8);
    int olds  = (int)(pk & 255u);
    const float* xr = x + (size_t)tokid * DMODEL;
    xrow[tid] = xr[tid];
    __syncthreads();
    const float* qr = qk + (size_t)tid * DMODEL;
    float a = 0.f;
#pragma unroll
    for (int d4 = 0; d4 < 64; ++d4) {   // strict sequential-d order (matches exact path)
      float4 qv = *(const float4*)(qr + d4 * 4);
      float4 xv = *(const float4*)(&xrow[d4 * 4]);
      a = fmaf(xv.x, qv.x, a); a = fmaf(xv.y, qv.y, a);
      a = fmaf(xv.z, qv.z, a); a = fmaf(xv.w, qv.w, a);
    }
    sv[tid] = a; si[tid] = tid;
    __syncthreads();
    for (int s = 128; s >= 1; s >>= 1) {
      if (tid < s) {
        float vo = sv[tid + s]; int io = si[tid + s];
        if (vo > sv[tid] || (vo == sv[tid] && io < si[tid])) { sv[tid] = vo; si[tid] = io; }
      }
      __syncthreads();
    }
    int news = si[0];
    if (news != olds) {
      int bb = tokid >> 13;
      if (tid == 0) {
        hard[(size_t)tokid * NQQ + olds] = 0.f;
        hard[(size_t)tokid * NQQ + news] = 1.f;
      }
      float xv = xrow[tid];
      atomicAdd(&S[((size_t)bb * NQQ + olds) * DMODEL + tid], -xv);
      atomicAdd(&S[((size_t)bb * NQQ + news) * DMODEL + tid],  xv);
    }
    __syncthreads();
  }
}

// out[b,s,d] = sum_dm S[b,s,dm] * MT[dm,d]
__global__ __launch_bounds__(256) void out_kernel(
    const float* __restrict__ S, const float* __restrict__ MT,
    float* __restrict__ out) {
  __shared__ float srow[8][DMODEL];
  const int tid = threadIdx.x;
  const int r0 = blockIdx.x * 8;
#pragma unroll
  for (int i = 0; i < 8; ++i) srow[i][tid] = S[(size_t)(r0 + i) * DMODEL + tid];
  __syncthreads();
  float a[8];
#pragma unroll
  for (int i = 0; i < 8; ++i) a[i] = 0.f;
  for (int dm = 0; dm < DMODEL; ++dm) {
    float m = MT[(size_t)dm * DMODEL + tid];
#pragma unroll
    for (int i = 0; i < 8; ++i) a[i] = fmaf(srow[i][dm], m, a[i]);
  }
#pragma unroll
  for (int i = 0; i < 8; ++i) out[(size_t)(r0 + i) * DMODEL + tid] = a[i];
}

extern "C" void kernel_launch(void* const* d_in, const int* in_sizes, int n_in,
                              void* d_out, int out_size, void* d_ws, size_t ws_size,
                              hipStream_t stream) {
  const float* x   = (const float*)d_in[0];
  const float* q   = (const float*)d_in[1];
  const float* wks = (const float*)d_in[2];
  const float* wvs = (const float*)d_in[3];
  const float* wfc = (const float*)d_in[4];

  float* out  = (float*)d_out;                       // (16,256,256)
  float* hard = out + (size_t)BB * NQQ * DMODEL;     // (16,8192,256)

  float* qk = (float*)d_ws;                          // 65536 f
  float* MT = qk + 65536;                            // 65536 f
  float* S  = MT + 65536;                            // 1048576 f (4 MB)
  unsigned* cnt  = (unsigned*)(S + 1048576);         // 64 u32 (pad)
  unsigned* list = cnt + 64;                         // CAP u32
  unsigned short* qhf = (unsigned short*)(list + CAP);  // 65536 bf16
  unsigned short* qlf = qhf + 65536;                    // 65536 bf16

  hipMemsetAsync(S, 0, (size_t)1048576 * sizeof(float), stream);
  hipMemsetAsync(cnt, 0, 256, stream);
  prep_kernel<<<2 * NQQ, 256, 0, stream>>>(q, wks, wvs, wfc, qk, MT, qhf, qlf);
  score_kernel<<<dim3(NN / TOK, BB), 256, 0, stream>>>(x, qhf, qlf, S, hard, cnt, list);
  recheck_kernel<<<2048, 256, 0, stream>>>(x, qk, cnt, list, S, hard);
  out_kernel<<<(BB * NQQ) / 8, 256, 0, stream>>>(S, MT, out);
}